// Round 9
// baseline (22489.059 us; speedup 1.0000x reference)
//
#include <hip/hip_runtime.h>

#define T_STEPS 100
#define IC      21
#define NS      7
#define CF      64
#define HID     128
#define EPS     1e-5f

// ---------------- ws layout (float offsets) ----------------
#define OFF_W0FH   0           // [512][448] bf16 hi, permuted k=p*64+oc
#define OFF_W0FL   114688
#define OFF_W0BH   229376
#define OFF_W0BL   344064
#define OFF_W1FBH  458752      // [512][256]: k<128 bf16hi | k>=128 f16
#define OFF_W1FBL  524288
#define OFF_W1BBH  589824
#define OFF_W1BBL  655360
#define OFF_W1T    720896      // 4032
#define OFF_W2T    724928      // 12288
#define OFF_SCALE1 737216
#define OFF_SHIFT1 737280
#define OFF_SCALE2 737344
#define OFF_SHIFT2 737408
#define OFF_BIASL0 737472      // fwd 512 | bwd 512
#define OFF_BIAS1F 738496
#define OFF_BIAS1B 739008
#define PARAM_END  739520
#define OFF_H1F    739520      // [512][128] f32
#define OFF_XP1B   805056      // [512][512] f32
#define OFF_FLAGS  1067200     // 1024 ints
#define OFF_SEQ1B  1460416     // [100][512][128] f16
#define OFF_CNND   4737216     // cnn 2x(H+L) shorts
#define OFF_XPRE0  5195968     // 2 x [512][512] f32
#define OFF_XPRE1  5720256
#define OFF_SEQF   6244544     // shorts: H0|L0|H1|L1 (each 65536)

#define NB_PREP    1441792
#define NF_PREP    19648

// flag indices
#define FC1 0
#define FG1 100
#define FS1 200
#define FC2 300
#define FG2 400
#define FS2 500
#define FG3 600
#define FS3 700
#define FXP 800

typedef __attribute__((ext_vector_type(8))) short short8;
typedef __attribute__((ext_vector_type(8))) _Float16 half8;
typedef __attribute__((ext_vector_type(4))) float f32x4;

__device__ __forceinline__ float sigmoidf_(float x) { return 1.0f / (1.0f + __expf(-x)); }
__device__ __forceinline__ float tanhf_(float x)    { return 2.0f / (1.0f + __expf(-2.0f * x)) - 1.0f; }

__device__ __forceinline__ unsigned short f2bf_rn(float f) {
    union { float f; unsigned int u; } v; v.f = f;
    unsigned int u = v.u;
    return (unsigned short)((u + 0x7FFFu + ((u >> 16) & 1u)) >> 16);
}
__device__ __forceinline__ float bf2f(unsigned short h) {
    union { unsigned int u; float f; } v; v.u = ((unsigned int)h) << 16;
    return v.f;
}
__device__ __forceinline__ unsigned short f2h_u(float f) {
    union { _Float16 h; unsigned short u; } v; v.h = (_Float16)f; return v.u;
}

__device__ __forceinline__ void gload16(const void* g, void* l) {
    __builtin_amdgcn_global_load_lds(
        (const __attribute__((address_space(1))) unsigned int*)g,
        (__attribute__((address_space(3))) unsigned int*)l, 16, 0, 0);
}

// ---- flag sync ----
__device__ __forceinline__ void waitf(int* f, int v) {
    if (threadIdx.x == 0) {
        while (__hip_atomic_load(f, __ATOMIC_RELAXED, __HIP_MEMORY_SCOPE_AGENT) < v)
            __builtin_amdgcn_s_sleep(2);
    }
    __syncthreads();
    __threadfence();
}
__device__ __forceinline__ void bumpf(int* f) {
    __syncthreads();
    __threadfence();
    if (threadIdx.x == 0) atomicAdd(f, 1);
}

// ---------------- prep (proven) ----------------
__global__ void prep_kernel(
    const float* __restrict__ c1w, const float* __restrict__ c1b,
    const float* __restrict__ g1, const float* __restrict__ b1,
    const float* __restrict__ m1, const float* __restrict__ v1,
    const float* __restrict__ c2w, const float* __restrict__ c2b,
    const float* __restrict__ g2, const float* __restrict__ b2,
    const float* __restrict__ m2, const float* __restrict__ v2,
    const float* __restrict__ wih0f, const float* __restrict__ wih0b,
    const float* __restrict__ wih1f, const float* __restrict__ wih1b,
    const float* __restrict__ bih0f, const float* __restrict__ bhh0f,
    const float* __restrict__ bih0b, const float* __restrict__ bhh0b,
    const float* __restrict__ bih1f, const float* __restrict__ bhh1f,
    const float* __restrict__ bih1b, const float* __restrict__ bhh1b,
    float* __restrict__ ws)
{
    unsigned short* wsH = (unsigned short*)ws;
    int stride = gridDim.x * blockDim.x;
    for (int i = blockIdx.x * blockDim.x + threadIdx.x;
         i < NB_PREP + NF_PREP; i += stride) {
        if (i < 917504) {
            int plane = i / 229376;
            int ii = i - plane * 229376;
            int n = ii / 448, kk = ii - n * 448;
            int p = kk >> 6, oc = kk & 63;
            const float* src = (plane < 2) ? wih0f : wih0b;
            float val = src[n * 448 + oc * 7 + p];
            int base = (plane == 0) ? OFF_W0FH : (plane == 1) ? OFF_W0FL
                     : (plane == 2) ? OFF_W0BH : OFF_W0BL;
            unsigned short hi = f2bf_rn(val);
            wsH[(size_t)base * 2 + ii] = (plane & 1) ? f2bf_rn(val - bf2f(hi)) : hi;
        } else if (i < NB_PREP) {
            int e = i - 917504;
            int plane = e / 131072;
            int ii = e - plane * 131072;
            int n = ii >> 8, k = ii & 255;
            const float* src = (plane < 2) ? wih1f : wih1b;
            float val = src[n * 256 + k];
            int base = (plane == 0) ? OFF_W1FBH : (plane == 1) ? OFF_W1FBL
                     : (plane == 2) ? OFF_W1BBH : OFF_W1BBL;
            unsigned short outv;
            if (k < 128) {
                unsigned short hi = f2bf_rn(val);
                outv = (plane & 1) ? f2bf_rn(val - bf2f(hi)) : hi;
            } else {
                outv = (plane & 1) ? (unsigned short)0 : f2h_u(val);
            }
            wsH[(size_t)base * 2 + ii] = outv;
        } else {
            int j = i - NB_PREP;
            if (j < 4032) {
                int oc = j & 63, w = j >> 6;
                ws[OFF_W1T + j] = c1w[oc * 63 + w];
            } else if (j < 16320) {
                int jj = j - 4032;
                int oc = jj & 63, w = jj >> 6;
                ws[OFF_W2T + jj] = c2w[oc * 192 + w];
            } else if (j < 16384) {
                int oc = j - 16320;
                ws[OFF_SCALE1 + oc] = g1[oc] * rsqrtf(v1[oc] + EPS);
            } else if (j < 16448) {
                int oc = j - 16384;
                float inv = g1[oc] * rsqrtf(v1[oc] + EPS);
                ws[OFF_SHIFT1 + oc] = c1b[oc] * inv + b1[oc] - m1[oc] * inv;
            } else if (j < 16512) {
                int oc = j - 16448;
                ws[OFF_SCALE2 + oc] = g2[oc] * rsqrtf(v2[oc] + EPS);
            } else if (j < 16576) {
                int oc = j - 16512;
                float inv = g2[oc] * rsqrtf(v2[oc] + EPS);
                ws[OFF_SHIFT2 + oc] = c2b[oc] * inv + b2[oc] - m2[oc] * inv;
            } else if (j < 17600) {
                int n = j - 16576;
                ws[OFF_BIASL0 + n] = (n < 512) ? (bih0f[n] + bhh0f[n])
                                               : (bih0b[n - 512] + bhh0b[n - 512]);
            } else if (j < 18112) {
                int n = j - 17600;
                ws[OFF_BIAS1F + n] = bih1f[n] + bhh1f[n];
            } else if (j < 18624) {
                int n = j - 18112;
                ws[OFF_BIAS1B + n] = bih1b[n] + bhh1b[n];
            } else {
                ((int*)(ws + OFF_FLAGS))[j - 18624] = 0;
            }
        }
    }
}

// ---------------- cnn body: 8 samples, 512 threads, NOINLINE ----------------
__device__ __attribute__((noinline)) void cnn_body8(
    const float* __restrict__ x, const float* __restrict__ ws,
    unsigned short* __restrict__ outH, unsigned short* __restrict__ outL,
    int t, int b0, char* smemc)
{
    float (*xs)[IC][12] = (float (*)[IC][12])smemc;
    float (*y1)[9][64]  = (float (*)[9][64])(smemc + 8064);
    int tid = threadIdx.x;
    int oc = tid & 63, s = tid >> 6;

    for (int i = tid; i < 8 * IC * 12; i += 512) ((float*)xs)[i] = 0.f;
    __syncthreads();
    for (int idx = tid; idx < 8 * 147; idx += 512) {
        int ss = idx / 147, e = idx - ss * 147;
        int ic = e / 7, px = e - ic * 7;
        xs[ss][ic][px + 1] = x[((size_t)(b0 + ss) * T_STEPS + t) * 147 + e];
    }
    __syncthreads();

    const float* w1t = ws + OFF_W1T;
    float acc1[7];
#pragma unroll
    for (int p = 0; p < 7; p++) acc1[p] = 0.f;
    for (int ic = 0; ic < IC; ic++) {
        float w0 = w1t[(ic * 3 + 0) * 64 + oc];
        float w1 = w1t[(ic * 3 + 1) * 64 + oc];
        float w2 = w1t[(ic * 3 + 2) * 64 + oc];
        const float* xr = &xs[s][ic][0];
        float4 xa = *(const float4*)xr;
        float4 xb = *(const float4*)(xr + 4);
        float x8 = xr[8];
        float xv[9] = {xa.x, xa.y, xa.z, xa.w, xb.x, xb.y, xb.z, xb.w, x8};
#pragma unroll
        for (int p = 0; p < 7; p++)
            acc1[p] += w0 * xv[p] + w1 * xv[p + 1] + w2 * xv[p + 2];
    }
    for (int i = tid; i < 1024; i += 512) {
        int ss = i >> 7, row = ((i >> 6) & 1) ? 8 : 0, o2 = i & 63;
        y1[ss][row][o2] = 0.f;
    }
    {
        float sc = ws[OFF_SCALE1 + oc], sh = ws[OFF_SHIFT1 + oc];
#pragma unroll
        for (int p = 0; p < 7; p++) {
            float v = acc1[p] * sc + sh;
            y1[s][p + 1][oc] = v > 0.f ? v : 0.f;
        }
    }
    __syncthreads();

    const float* w2t = ws + OFF_W2T;
    float acc2[7];
#pragma unroll
    for (int p = 0; p < 7; p++) acc2[p] = 0.f;
    for (int c4 = 0; c4 < 16; c4++) {
        float wv[12];
#pragma unroll
        for (int cc = 0; cc < 4; cc++)
#pragma unroll
            for (int k = 0; k < 3; k++)
                wv[cc * 3 + k] = w2t[((c4 * 4 + cc) * 3 + k) * 64 + oc];
        float4 yv[9];
#pragma unroll
        for (int r = 0; r < 9; r++) yv[r] = *(const float4*)&y1[s][r][c4 * 4];
#pragma unroll
        for (int p = 0; p < 7; p++) {
            float a = 0.f;
#pragma unroll
            for (int k = 0; k < 3; k++) {
                float4 yy = yv[p + k];
                a += wv[0 * 3 + k] * yy.x + wv[1 * 3 + k] * yy.y
                   + wv[2 * 3 + k] * yy.z + wv[3 * 3 + k] * yy.w;
            }
            acc2[p] += a;
        }
    }
    {
        float sc = ws[OFF_SCALE2 + oc], sh = ws[OFF_SHIFT2 + oc];
#pragma unroll
        for (int p = 0; p < 7; p++) {
            float v = acc2[p] * sc + sh;
            v = v > 0.f ? v : 0.f;
            unsigned short hi = f2bf_rn(v);
            unsigned short lo = f2bf_rn(v - bf2f(hi));
            size_t o = (size_t)(b0 + s) * 448 + p * 64 + oc;
            outH[o] = hi; outL[o] = lo;
        }
    }
    __syncthreads();
}

// ---------------- gemm body (proven hybrid; 512 threads; NOINLINE) ----------------
__device__ __attribute__((noinline)) void gemm_body(
    const unsigned short* __restrict__ A0h, const unsigned short* __restrict__ A0l,
    int lda0, int K0,
    const _Float16* __restrict__ A1, int lda1,
    const unsigned short* __restrict__ Bh, const unsigned short* __restrict__ Bl,
    const float* __restrict__ bias, float* __restrict__ outp, int K,
    int idx, char* smemc)
{
    unsigned short* lAh = (unsigned short*)smemc;
    unsigned short* lAl = lAh + 4096;
    unsigned short* lBh = lAh + 8192;
    unsigned short* lBl = lAh + 12288;

    int tid = threadIdx.x;
    bool act = tid < 256;
    int m0 = (idx >> 2) * 128, n0 = (idx & 3) * 128;
    int l = tid & 63, w = tid >> 6;
    int wm = (w >> 1) & 1, wn = w & 1;
    int lr = l & 15, lk = l >> 4;
    int srow = (w & 3) * 16 + (l >> 2);
    int skoff = (l & 3) * 8;

    f32x4 acc[4][4];
#pragma unroll
    for (int i = 0; i < 4; i++)
#pragma unroll
        for (int j = 0; j < 4; j++) acc[i][j] = (f32x4){0.f, 0.f, 0.f, 0.f};

    for (int kt = 0; kt < K; kt += 32) {
        bool seg0 = (kt < K0);
        __syncthreads();
        if (w < 4) {
#pragma unroll
            for (int hh = 0; hh < 2; hh++) {
                size_t arow = (size_t)(m0 + hh * 64 + srow);
                size_t brow = (size_t)(n0 + hh * 64 + srow);
                char* dA  = (char*)lAh + hh * 4096 + w * 1024;
                char* dAl = (char*)lAl + hh * 4096 + w * 1024;
                char* dB  = (char*)lBh + hh * 4096 + w * 1024;
                char* dBl = (char*)lBl + hh * 4096 + w * 1024;
                if (seg0) {
                    gload16(A0h + arow * lda0 + kt + skoff, dA);
                    gload16(A0l + arow * lda0 + kt + skoff, dAl);
                    gload16(Bl + brow * K + kt + skoff, dBl);
                } else {
                    gload16(A1 + arow * lda1 + (kt - K0) + skoff, dA);
                }
                gload16(Bh + brow * K + kt + skoff, dB);
            }
        }
        __syncthreads();

        if (act) {
            if (seg0) {
                short8 fah[4], fal[4], fbh[4], fbl[4];
#pragma unroll
                for (int mf = 0; mf < 4; mf++) {
                    int row = wm * 64 + mf * 16 + lr;
                    fah[mf] = *(const short8*)&lAh[row * 32 + lk * 8];
                    fal[mf] = *(const short8*)&lAl[row * 32 + lk * 8];
                }
#pragma unroll
                for (int nf = 0; nf < 4; nf++) {
                    int row = wn * 64 + nf * 16 + lr;
                    fbh[nf] = *(const short8*)&lBh[row * 32 + lk * 8];
                    fbl[nf] = *(const short8*)&lBl[row * 32 + lk * 8];
                }
#pragma unroll
                for (int mf = 0; mf < 4; mf++)
#pragma unroll
                    for (int nf = 0; nf < 4; nf++) {
                        acc[mf][nf] = __builtin_amdgcn_mfma_f32_16x16x32_bf16(
                            fah[mf], fbh[nf], acc[mf][nf], 0, 0, 0);
                        acc[mf][nf] = __builtin_amdgcn_mfma_f32_16x16x32_bf16(
                            fah[mf], fbl[nf], acc[mf][nf], 0, 0, 0);
                        acc[mf][nf] = __builtin_amdgcn_mfma_f32_16x16x32_bf16(
                            fal[mf], fbh[nf], acc[mf][nf], 0, 0, 0);
                    }
            } else {
                half8 fah[4], fbh[4];
#pragma unroll
                for (int mf = 0; mf < 4; mf++) {
                    int row = wm * 64 + mf * 16 + lr;
                    fah[mf] = *(const half8*)&lAh[row * 32 + lk * 8];
                }
#pragma unroll
                for (int nf = 0; nf < 4; nf++) {
                    int row = wn * 64 + nf * 16 + lr;
                    fbh[nf] = *(const half8*)&lBh[row * 32 + lk * 8];
                }
#pragma unroll
                for (int mf = 0; mf < 4; mf++)
#pragma unroll
                    for (int nf = 0; nf < 4; nf++)
                        acc[mf][nf] = __builtin_amdgcn_mfma_f32_16x16x32_f16(
                            fah[mf], fbh[nf], acc[mf][nf], 0, 0, 0);
            }
        }
    }

    if (act) {
#pragma unroll
        for (int nf = 0; nf < 4; nf++) {
            int gcol = n0 + wn * 64 + nf * 16 + lr;
            float bv = bias[gcol];
#pragma unroll
            for (int mf = 0; mf < 4; mf++) {
                int grow = m0 + wm * 64 + mf * 16 + lk * 4;
#pragma unroll
                for (int q = 0; q < 4; q++)
                    outp[(size_t)(grow + q) * 512 + gcol] = acc[mf][nf][q] + bv;
            }
        }
    }
    __syncthreads();
}

// ---------------- mega: persistent pipeline ----------------
__global__ __launch_bounds__(512) void mega(
    const float* __restrict__ x, float* __restrict__ ws,
    const float* __restrict__ whh0f, const float* __restrict__ whh0b,
    const float* __restrict__ whh1f,
    const float* __restrict__ fc1w, const float* __restrict__ fc1b,
    const float* __restrict__ fc2w, const float* __restrict__ fc2b,
    float* __restrict__ out)
{
    __shared__ __align__(16) char smem[32768];
    const int blk = blockIdx.x;
    int* F = (int*)(ws + OFF_FLAGS);
    unsigned short* wsH = (unsigned short*)ws;

    unsigned short* cnnH0 = wsH + (size_t)OFF_CNND * 2;
    unsigned short* cnnL0 = cnnH0 + 229376;
    unsigned short* cnnH1 = cnnH0 + 458752;
    unsigned short* cnnL1 = cnnH1 + 229376;
    float* xpre0[2] = { ws + OFF_XPRE0, ws + OFF_XPRE0 + 262144 };
    float* xpre1[2] = { ws + OFF_XPRE1, ws + OFF_XPRE1 + 262144 };
    unsigned short* sfH0 = wsH + (size_t)OFF_SEQF * 2;
    unsigned short* sfL0 = sfH0 + 65536;
    unsigned short* sfH1 = sfH0 + 131072;
    unsigned short* sfL1 = sfH1 + 65536;
    _Float16* seq1b = (_Float16*)(ws + OFF_SEQ1B);

    const unsigned short* W0FH = wsH + (size_t)OFF_W0FH * 2;
    const unsigned short* W0FL = wsH + (size_t)OFF_W0FL * 2;
    const unsigned short* W0BH = wsH + (size_t)OFF_W0BH * 2;
    const unsigned short* W0BL = wsH + (size_t)OFF_W0BL * 2;
    const unsigned short* W1FBH = wsH + (size_t)OFF_W1FBH * 2;
    const unsigned short* W1FBL = wsH + (size_t)OFF_W1FBL * 2;
    const unsigned short* W1BBH = wsH + (size_t)OFF_W1BBH * 2;
    const unsigned short* W1BBL = wsH + (size_t)OFF_W1BBL * 2;

    if (blk < 128) {
        float* smf = (float*)smem;
        int g = threadIdx.x;
        // ---- phase 1: R=4, whh0b, all 128 scan blocks ----
        {
            float w[128];
#pragma unroll
            for (int k = 0; k < 128; k += 4) {
                float4 wv = *(const float4*)&whh0b[(size_t)g * 128 + k];
                w[k] = wv.x; w[k + 1] = wv.y; w[k + 2] = wv.z; w[k + 3] = wv.w;
            }
            float* hl = smf;
            float* cl = smf + 512;
            float* gl = smf + 1024;
            hl[g] = 0.f; cl[g] = 0.f;
            __syncthreads();
            int r0 = blk * 4;
            for (int i = 0; i < 100; i++) {
                waitf(&F[FG1 + i], 16);
                const float* xp = xpre0[i & 1];
                float a0 = xp[(size_t)(r0 + 0) * 512 + g];
                float a1 = xp[(size_t)(r0 + 1) * 512 + g];
                float a2 = xp[(size_t)(r0 + 2) * 512 + g];
                float a3 = xp[(size_t)(r0 + 3) * 512 + g];
#pragma unroll
                for (int k = 0; k < 128; k += 4) {
                    float4 h0 = *(const float4*)&hl[0 * 128 + k];
                    float4 h1 = *(const float4*)&hl[1 * 128 + k];
                    float4 h2 = *(const float4*)&hl[2 * 128 + k];
                    float4 h3 = *(const float4*)&hl[3 * 128 + k];
                    a0 += w[k] * h0.x + w[k + 1] * h0.y + w[k + 2] * h0.z + w[k + 3] * h0.w;
                    a1 += w[k] * h1.x + w[k + 1] * h1.y + w[k + 2] * h1.z + w[k + 3] * h1.w;
                    a2 += w[k] * h2.x + w[k + 1] * h2.y + w[k + 2] * h2.z + w[k + 3] * h2.w;
                    a3 += w[k] * h3.x + w[k + 1] * h3.y + w[k + 2] * h3.z + w[k + 3] * h3.w;
                }
                gl[g] = a0; gl[512 + g] = a1; gl[1024 + g] = a2; gl[1536 + g] = a3;
                __syncthreads();
                {
                    int r = g >> 7, j = g & 127;
                    float gi = sigmoidf_(gl[r * 512 + j]);
                    float gf = sigmoidf_(gl[r * 512 + 128 + j]);
                    float gg = tanhf_(gl[r * 512 + 256 + j]);
                    float go = sigmoidf_(gl[r * 512 + 384 + j]);
                    float c = gf * cl[r * 128 + j] + gi * gg;
                    cl[r * 128 + j] = c;
                    float h = go * tanhf_(c);
                    hl[r * 128 + j] = h;
                    seq1b[((size_t)(99 - i) * 512 + r0 + r) * 128 + j] = (_Float16)h;
                }
                bumpf(&F[FS1 + i]);
            }
        }
        // ---- phase 2 ----
        if (blk < 64) {
            // l0 forward, R=8
            float w[128];
#pragma unroll
            for (int k = 0; k < 128; k += 4) {
                float4 wv = *(const float4*)&whh0f[(size_t)g * 128 + k];
                w[k] = wv.x; w[k + 1] = wv.y; w[k + 2] = wv.z; w[k + 3] = wv.w;
            }
            float* hl = smf;
            float* cl = smf + 1024;
            float* gl = smf + 2048;
            hl[g] = 0.f; hl[g + 512] = 0.f;
            cl[g] = 0.f; cl[g + 512] = 0.f;
            __syncthreads();
            int r0 = blk * 8;
            for (int i = 0; i < 100; i++) {
                waitf(&F[FG2 + i], 16);
                if (i >= 2) waitf(&F[FG3 + i - 2], 16);
                const float* xp = xpre0[i & 1];
                float acc[8];
#pragma unroll
                for (int r = 0; r < 8; r++) acc[r] = xp[(size_t)(r0 + r) * 512 + g];
#pragma unroll
                for (int k = 0; k < 128; k += 4) {
#pragma unroll
                    for (int r = 0; r < 8; r++) {
                        float4 hv = *(const float4*)&hl[r * 128 + k];
                        acc[r] += w[k] * hv.x + w[k + 1] * hv.y
                                + w[k + 2] * hv.z + w[k + 3] * hv.w;
                    }
                }
#pragma unroll
                for (int r = 0; r < 8; r++) gl[r * 512 + g] = acc[r];
                __syncthreads();
                unsigned short* oH = (i & 1) ? sfH1 : sfH0;
                unsigned short* oL = (i & 1) ? sfL1 : sfL0;
#pragma unroll
                for (int u = 0; u < 2; u++) {
                    int idx = g + u * 512;
                    int r = idx >> 7, j = idx & 127;
                    float gi = sigmoidf_(gl[r * 512 + j]);
                    float gf = sigmoidf_(gl[r * 512 + 128 + j]);
                    float gg = tanhf_(gl[r * 512 + 256 + j]);
                    float go = sigmoidf_(gl[r * 512 + 384 + j]);
                    float c = gf * cl[r * 128 + j] + gi * gg;
                    cl[r * 128 + j] = c;
                    float h = go * tanhf_(c);
                    hl[r * 128 + j] = h;
                    size_t o = (size_t)(r0 + r) * 128 + j;
                    unsigned short hi = f2bf_rn(h);
                    oH[o] = hi;
                    oL[o] = f2bf_rn(h - bf2f(hi));
                }
                bumpf(&F[FS2 + i]);
            }
        } else {
            // l1 forward, R=8
            float w[128];
#pragma unroll
            for (int k = 0; k < 128; k += 4) {
                float4 wv = *(const float4*)&whh1f[(size_t)g * 128 + k];
                w[k] = wv.x; w[k + 1] = wv.y; w[k + 2] = wv.z; w[k + 3] = wv.w;
            }
            float* hl = smf;
            float* cl = smf + 1024;
            float* gl = smf + 2048;
            hl[g] = 0.f; hl[g + 512] = 0.f;
            cl[g] = 0.f; cl[g + 512] = 0.f;
            __syncthreads();
            int r0 = (blk - 64) * 8;
            for (int i = 0; i < 100; i++) {
                waitf(&F[FG3 + i], 16);
                const float* xp = xpre1[i & 1];
                float acc[8];
#pragma unroll
                for (int r = 0; r < 8; r++) acc[r] = xp[(size_t)(r0 + r) * 512 + g];
#pragma unroll
                for (int k = 0; k < 128; k += 4) {
#pragma unroll
                    for (int r = 0; r < 8; r++) {
                        float4 hv = *(const float4*)&hl[r * 128 + k];
                        acc[r] += w[k] * hv.x + w[k + 1] * hv.y
                                + w[k + 2] * hv.z + w[k + 3] * hv.w;
                    }
                }
#pragma unroll
                for (int r = 0; r < 8; r++) gl[r * 512 + g] = acc[r];
                __syncthreads();
#pragma unroll
                for (int u = 0; u < 2; u++) {
                    int idx = g + u * 512;
                    int r = idx >> 7, j = idx & 127;
                    float gi = sigmoidf_(gl[r * 512 + j]);
                    float gf = sigmoidf_(gl[r * 512 + 128 + j]);
                    float gg = tanhf_(gl[r * 512 + 256 + j]);
                    float go = sigmoidf_(gl[r * 512 + 384 + j]);
                    float c = gf * cl[r * 128 + j] + gi * gg;
                    cl[r * 128 + j] = c;
                    float h = go * tanhf_(c);
                    hl[r * 128 + j] = h;
                    if (i == T_STEPS - 1)
                        (ws + OFF_H1F)[(size_t)(r0 + r) * 128 + j] = h;
                }
                bumpf(&F[FS3 + i]);
            }
        }
    } else if (blk < 192) {
        // ================= CNN (64 blocks x 8 samples) =================
        int b0 = (blk - 128) * 8;
        for (int i = 0; i < 100; i++) {
            if (i >= 2) waitf(&F[FG1 + i - 2], 16);
            cnn_body8(x, ws, (i & 1) ? cnnH1 : cnnH0, (i & 1) ? cnnL1 : cnnL0,
                      99 - i, b0, smem);
            bumpf(&F[FC1 + i]);
        }
        for (int i = 0; i < 100; i++) {
            if (i < 2) waitf(&F[FG1 + 98 + i], 16);
            else       waitf(&F[FG2 + i - 2], 16);
            cnn_body8(x, ws, (i & 1) ? cnnH1 : cnnH0, (i & 1) ? cnnL1 : cnnL0,
                      i, b0, smem);
            bumpf(&F[FC2 + i]);
        }
    } else if (blk < 208) {
        // ================= GEMM0 (16 blocks) =================
        int idx = blk - 192;
        for (int i = 0; i < 100; i++) {
            waitf(&F[FC1 + i], 64);
            if (i >= 2) waitf(&F[FS1 + i - 2], 128);
            gemm_body((i & 1) ? cnnH1 : cnnH0, (i & 1) ? cnnL1 : cnnL0, 448, 448,
                      (const _Float16*)nullptr, 0,
                      W0BH, W0BL, ws + OFF_BIASL0 + 512, xpre0[i & 1], 448, idx, smem);
            bumpf(&F[FG1 + i]);
        }
        for (int i = 0; i < 100; i++) {
            waitf(&F[FC2 + i], 64);
            if (i < 2) waitf(&F[FS1 + 98 + i], 128);
            else       waitf(&F[FS2 + i - 2], 64);
            gemm_body((i & 1) ? cnnH1 : cnnH0, (i & 1) ? cnnL1 : cnnL0, 448, 448,
                      (const _Float16*)nullptr, 0,
                      W0FH, W0FL, ws + OFF_BIASL0, xpre0[i & 1], 448, idx, smem);
            bumpf(&F[FG2 + i]);
        }
        // tail: xp1b = [seqf(t=99) | seq1b(t=99)] @ W1BB
        waitf(&F[FS2 + 99], 64);
        gemm_body(sfH1, sfL1, 128, 128, seq1b + (size_t)99 * 65536, 128,
                  W1BBH, W1BBL, ws + OFF_BIAS1B, ws + OFF_XP1B, 256, idx, smem);
        bumpf(&F[FXP]);
    } else if (blk < 224) {
        // ================= GEMM1 (16 blocks, phase 2 only) =================
        int idx = blk - 208;
        for (int i = 0; i < 100; i++) {
            waitf(&F[FS2 + i], 64);
            waitf(&F[FS1 + 99 - i], 128);
            if (i >= 2) waitf(&F[FS3 + i - 2], 64);
            gemm_body((i & 1) ? sfH1 : sfH0, (i & 1) ? sfL1 : sfL0, 128, 128,
                      seq1b + (size_t)i * 65536, 128,
                      W1FBH, W1FBL, ws + OFF_BIAS1F, xpre1[i & 1], 256, idx, smem);
            bumpf(&F[FG3 + i]);
        }
    } else {
        // ================= FINAL head (blk == 224) =================
        waitf(&F[FXP], 16);
        waitf(&F[FS3 + 99], 64);
        float (*last)[256] = (float (*)[256])smem;
        float (*f1)[64] = (float (*)[64])(smem + 8192);
        const float* xp1b = ws + OFF_XP1B;
        const float* h1f  = ws + OFF_H1F;
        int tid = threadIdx.x;
        int grp = tid >> 6, t64 = tid & 63;
        for (int bb = 0; bb < 64; bb++) {
            int b = bb * 8 + grp;
#pragma unroll
            for (int q = 0; q < 2; q++) {
                int j = t64 + q * 64;
                last[grp][j] = h1f[(size_t)b * 128 + j];
                float gi = sigmoidf_(xp1b[(size_t)b * 512 + j]);
                float gg = tanhf_(xp1b[(size_t)b * 512 + 256 + j]);
                float go = sigmoidf_(xp1b[(size_t)b * 512 + 384 + j]);
                float c = gi * gg;
                last[grp][128 + j] = go * tanhf_(c);
            }
            __syncthreads();
            float a = fc1b[t64];
            for (int k = 0; k < 256; k++) a += last[grp][k] * fc1w[t64 * 256 + k];
            f1[grp][t64] = a > 0.f ? a : 0.f;
            __syncthreads();
            if (t64 < 2) {
                float a2 = fc2b[t64];
                for (int k = 0; k < 64; k++) a2 += f1[grp][k] * fc2w[t64 * 64 + k];
                out[b * 2 + t64] = a2;
            }
            __syncthreads();
        }
    }
}

extern "C" void kernel_launch(void* const* d_in, const int* in_sizes, int n_in,
                              void* d_out, int out_size, void* d_ws, size_t ws_size,
                              hipStream_t stream)
{
    const float* x     = (const float*)d_in[0];
    const float* c1w   = (const float*)d_in[1];
    const float* c1b   = (const float*)d_in[2];
    const float* g1    = (const float*)d_in[3];
    const float* b1    = (const float*)d_in[4];
    const float* m1    = (const float*)d_in[5];
    const float* v1    = (const float*)d_in[6];
    const float* c2w   = (const float*)d_in[7];
    const float* c2b   = (const float*)d_in[8];
    const float* g2    = (const float*)d_in[9];
    const float* b2    = (const float*)d_in[10];
    const float* m2    = (const float*)d_in[11];
    const float* v2    = (const float*)d_in[12];
    const float* wih0f = (const float*)d_in[13];
    const float* whh0f = (const float*)d_in[14];
    const float* bih0f = (const float*)d_in[15];
    const float* bhh0f = (const float*)d_in[16];
    const float* wih0b = (const float*)d_in[17];
    const float* whh0b = (const float*)d_in[18];
    const float* bih0b = (const float*)d_in[19];
    const float* bhh0b = (const float*)d_in[20];
    const float* wih1f = (const float*)d_in[21];
    const float* whh1f = (const float*)d_in[22];
    const float* bih1f = (const float*)d_in[23];
    const float* bhh1f = (const float*)d_in[24];
    const float* wih1b = (const float*)d_in[25];
    const float* bih1b = (const float*)d_in[27];
    const float* bhh1b = (const float*)d_in[28];
    const float* fc1w  = (const float*)d_in[29];
    const float* fc1b  = (const float*)d_in[30];
    const float* fc2w  = (const float*)d_in[31];
    const float* fc2b  = (const float*)d_in[32];

    float* ws  = (float*)d_ws;
    float* out = (float*)d_out;

    hipLaunchKernelGGL(prep_kernel, dim3(5709), dim3(256), 0, stream,
                       c1w, c1b, g1, b1, m1, v1, c2w, c2b, g2, b2, m2, v2,
                       wih0f, wih0b, wih1f, wih1b,
                       bih0f, bhh0f, bih0b, bhh0b, bih1f, bhh1f, bih1b, bhh1b, ws);

    hipLaunchKernelGGL(mega, dim3(225), dim3(512), 0, stream,
                       x, ws, whh0f, whh0b, whh1f, fc1w, fc1b, fc2w, fc2b, out);

    (void)in_sizes; (void)n_in; (void)out_size; (void)ws_size;
}

// Round 10
// 12564.414 us; speedup vs baseline: 1.7899x; 1.7899x over previous
//
#include <hip/hip_runtime.h>

#define T_STEPS 100
#define IC      21
#define NS      7
#define CF      64
#define HID     128
#define EPS     1e-5f

// ---------------- ws layout (float offsets) ----------------
#define OFF_W0FH   0           // [512][448] bf16 hi, permuted k=p*64+oc
#define OFF_W0FL   114688
#define OFF_W0BH   229376
#define OFF_W0BL   344064
#define OFF_W1FBH  458752      // [512][256]: k<128 bf16hi | k>=128 f16
#define OFF_W1FBL  524288
#define OFF_W1BBH  589824
#define OFF_W1BBL  655360
#define OFF_W1T    720896      // 4032
#define OFF_W2T    724928      // 12288
#define OFF_SCALE1 737216
#define OFF_SHIFT1 737280
#define OFF_SCALE2 737344
#define OFF_SHIFT2 737408
#define OFF_BIASL0 737472      // fwd 512 | bwd 512
#define OFF_BIAS1F 738496
#define OFF_BIAS1B 739008
#define PARAM_END  739520
#define OFF_H1F    739520      // [512][128] f32
#define OFF_XP1B   805056      // [512][512] f32
#define OFF_STATE  1067200     // 6 x [512][128] f32 (h0b,c0b,h0f,c0f,h1f,c1f)
#define ZERO_TOTAL 393216
#define OFF_SEQ1B  1460416     // [100][512][128] f16 (3276800 floats)
// dynamic (TC=1 fixed):
#define OFF_CNNHL  4737216     // shorts: H 229376 | L 229376  (229376 floats)
#define OFF_XPRE0  4966592     // [512][512] f32
#define OFF_XPRE1  5228736     // [512][512] f32
#define OFF_SEQF   5490880     // shorts: H 65536 | L 65536    (65536 floats)
// end = 5556416 floats = 22.2 MB  (ws >= 34.3 MB proven)

#define NB_PREP    1441792
#define NF_PREP    411840

typedef __attribute__((ext_vector_type(8))) short short8;
typedef __attribute__((ext_vector_type(8))) _Float16 half8;
typedef __attribute__((ext_vector_type(4))) float f32x4;

__device__ __forceinline__ float sigmoidf_(float x) { return 1.0f / (1.0f + __expf(-x)); }
__device__ __forceinline__ float tanhf_(float x)    { return 2.0f / (1.0f + __expf(-2.0f * x)) - 1.0f; }

__device__ __forceinline__ unsigned short f2bf_rn(float f) {
    union { float f; unsigned int u; } v; v.f = f;
    unsigned int u = v.u;
    return (unsigned short)((u + 0x7FFFu + ((u >> 16) & 1u)) >> 16);
}
__device__ __forceinline__ float bf2f(unsigned short h) {
    union { unsigned int u; float f; } v; v.u = ((unsigned int)h) << 16;
    return v.f;
}
__device__ __forceinline__ unsigned short f2h_u(float f) {
    union { _Float16 h; unsigned short u; } v; v.h = (_Float16)f; return v.u;
}

__device__ __forceinline__ void gload16(const void* g, void* l) {
    __builtin_amdgcn_global_load_lds(
        (const __attribute__((address_space(1))) unsigned int*)g,
        (__attribute__((address_space(3))) unsigned int*)l, 16, 0, 0);
}

// ---------------- prep (R6-proven: weights + BN fold + state zero) ----------------
__global__ void prep_kernel(
    const float* __restrict__ c1w, const float* __restrict__ c1b,
    const float* __restrict__ g1, const float* __restrict__ b1,
    const float* __restrict__ m1, const float* __restrict__ v1,
    const float* __restrict__ c2w, const float* __restrict__ c2b,
    const float* __restrict__ g2, const float* __restrict__ b2,
    const float* __restrict__ m2, const float* __restrict__ v2,
    const float* __restrict__ wih0f, const float* __restrict__ wih0b,
    const float* __restrict__ wih1f, const float* __restrict__ wih1b,
    const float* __restrict__ bih0f, const float* __restrict__ bhh0f,
    const float* __restrict__ bih0b, const float* __restrict__ bhh0b,
    const float* __restrict__ bih1f, const float* __restrict__ bhh1f,
    const float* __restrict__ bih1b, const float* __restrict__ bhh1b,
    float* __restrict__ ws)
{
    unsigned short* wsH = (unsigned short*)ws;
    int stride = gridDim.x * blockDim.x;
    for (int i = blockIdx.x * blockDim.x + threadIdx.x;
         i < NB_PREP + NF_PREP; i += stride) {
        if (i < 917504) {                       // wih0 f/b, 4 planes, permuted
            int plane = i / 229376;
            int ii = i - plane * 229376;
            int n = ii / 448, kk = ii - n * 448;
            int p = kk >> 6, oc = kk & 63;
            const float* src = (plane < 2) ? wih0f : wih0b;
            float val = src[n * 448 + oc * 7 + p];
            int base = (plane == 0) ? OFF_W0FH : (plane == 1) ? OFF_W0FL
                     : (plane == 2) ? OFF_W0BH : OFF_W0BL;
            unsigned short hi = f2bf_rn(val);
            wsH[(size_t)base * 2 + ii] = (plane & 1) ? f2bf_rn(val - bf2f(hi)) : hi;
        } else if (i < NB_PREP) {               // wih1 f/b hybrid planes
            int e = i - 917504;
            int plane = e / 131072;
            int ii = e - plane * 131072;
            int n = ii >> 8, k = ii & 255;
            const float* src = (plane < 2) ? wih1f : wih1b;
            float val = src[n * 256 + k];
            int base = (plane == 0) ? OFF_W1FBH : (plane == 1) ? OFF_W1FBL
                     : (plane == 2) ? OFF_W1BBH : OFF_W1BBL;
            unsigned short outv;
            if (k < 128) {
                unsigned short hi = f2bf_rn(val);
                outv = (plane & 1) ? f2bf_rn(val - bf2f(hi)) : hi;
            } else {
                outv = (plane & 1) ? (unsigned short)0 : f2h_u(val);
            }
            wsH[(size_t)base * 2 + ii] = outv;
        } else {
            int j = i - NB_PREP;
            if (j < 4032) {
                int oc = j & 63, w = j >> 6;
                ws[OFF_W1T + j] = c1w[oc * 63 + w];
            } else if (j < 16320) {
                int jj = j - 4032;
                int oc = jj & 63, w = jj >> 6;
                ws[OFF_W2T + jj] = c2w[oc * 192 + w];
            } else if (j < 16384) {
                int oc = j - 16320;
                ws[OFF_SCALE1 + oc] = g1[oc] * rsqrtf(v1[oc] + EPS);
            } else if (j < 16448) {
                int oc = j - 16384;
                float inv = g1[oc] * rsqrtf(v1[oc] + EPS);
                ws[OFF_SHIFT1 + oc] = c1b[oc] * inv + b1[oc] - m1[oc] * inv;
            } else if (j < 16512) {
                int oc = j - 16448;
                ws[OFF_SCALE2 + oc] = g2[oc] * rsqrtf(v2[oc] + EPS);
            } else if (j < 16576) {
                int oc = j - 16512;
                float inv = g2[oc] * rsqrtf(v2[oc] + EPS);
                ws[OFF_SHIFT2 + oc] = c2b[oc] * inv + b2[oc] - m2[oc] * inv;
            } else if (j < 17600) {
                int n = j - 16576;
                ws[OFF_BIASL0 + n] = (n < 512) ? (bih0f[n] + bhh0f[n])
                                               : (bih0b[n - 512] + bhh0b[n - 512]);
            } else if (j < 18112) {
                int n = j - 17600;
                ws[OFF_BIAS1F + n] = bih1f[n] + bhh1f[n];
            } else if (j < 18624) {
                int n = j - 18112;
                ws[OFF_BIAS1B + n] = bih1b[n] + bhh1b[n];
            } else {
                ws[OFF_STATE + (j - 18624)] = 0.f;
            }
        }
    }
}

// ---------------- fused CNN, R4-proven 256-thread, TC=1 (grid 32) ----------------
__global__ __launch_bounds__(256) void cnn_kernel(
    const float* __restrict__ x, const float* __restrict__ ws,
    unsigned short* __restrict__ outH, unsigned short* __restrict__ outL, int t)
{
    __shared__ __align__(16) float xs[16][IC][12];
    __shared__ __align__(16) float y1[16][9][64];

    int tid = threadIdx.x;
    int oc = tid & 63, sq = tid >> 6;
    int rbase = blockIdx.x * 16;
    int b0 = rbase;

    for (int i = tid; i < 16 * IC * 12; i += 256) ((float*)xs)[i] = 0.f;
    __syncthreads();
    for (int idx = tid; idx < 16 * 147; idx += 256) {
        int s = idx / 147, e = idx - s * 147;
        int ic = e / 7, px = e - ic * 7;
        xs[s][ic][px + 1] = x[((size_t)(b0 + s) * T_STEPS + t) * 147 + e];
    }
    __syncthreads();

    const float* w1t = ws + OFF_W1T;
    float acc1[4][7];
#pragma unroll
    for (int si = 0; si < 4; si++)
#pragma unroll
        for (int p = 0; p < 7; p++) acc1[si][p] = 0.f;

    for (int ic = 0; ic < IC; ic++) {
        float w0 = w1t[(ic * 3 + 0) * 64 + oc];
        float w1 = w1t[(ic * 3 + 1) * 64 + oc];
        float w2 = w1t[(ic * 3 + 2) * 64 + oc];
#pragma unroll
        for (int si = 0; si < 4; si++) {
            int s = 4 * sq + si;
            const float* xr = &xs[s][ic][0];
            float4 xa = *(const float4*)xr;
            float4 xb = *(const float4*)(xr + 4);
            float x8 = xr[8];
            float xv[9] = {xa.x, xa.y, xa.z, xa.w, xb.x, xb.y, xb.z, xb.w, x8};
#pragma unroll
            for (int p = 0; p < 7; p++)
                acc1[si][p] += w0 * xv[p] + w1 * xv[p + 1] + w2 * xv[p + 2];
        }
    }
    for (int i = tid; i < 2048; i += 256) {
        int s = i >> 7, row = ((i >> 6) & 1) ? 8 : 0, o2 = i & 63;
        y1[s][row][o2] = 0.f;
    }
    {
        float sc = ws[OFF_SCALE1 + oc], sh = ws[OFF_SHIFT1 + oc];
#pragma unroll
        for (int si = 0; si < 4; si++) {
            int s = 4 * sq + si;
#pragma unroll
            for (int p = 0; p < 7; p++) {
                float v = acc1[si][p] * sc + sh;
                y1[s][p + 1][oc] = v > 0.f ? v : 0.f;
            }
        }
    }
    __syncthreads();

    const float* w2t = ws + OFF_W2T;
    float acc2[4][7];
#pragma unroll
    for (int si = 0; si < 4; si++)
#pragma unroll
        for (int p = 0; p < 7; p++) acc2[si][p] = 0.f;

    for (int c4 = 0; c4 < 16; c4++) {
        float wv[12];
#pragma unroll
        for (int cc = 0; cc < 4; cc++)
#pragma unroll
            for (int k = 0; k < 3; k++)
                wv[cc * 3 + k] = w2t[((c4 * 4 + cc) * 3 + k) * 64 + oc];
#pragma unroll
        for (int si = 0; si < 4; si++) {
            int s = 4 * sq + si;
            float4 yv[9];
#pragma unroll
            for (int r = 0; r < 9; r++) yv[r] = *(const float4*)&y1[s][r][c4 * 4];
#pragma unroll
            for (int p = 0; p < 7; p++) {
                float a = 0.f;
#pragma unroll
                for (int k = 0; k < 3; k++) {
                    float4 yy = yv[p + k];
                    a += wv[0 * 3 + k] * yy.x + wv[1 * 3 + k] * yy.y
                       + wv[2 * 3 + k] * yy.z + wv[3 * 3 + k] * yy.w;
                }
                acc2[si][p] += a;
            }
        }
    }
    {
        float sc = ws[OFF_SCALE2 + oc], sh = ws[OFF_SHIFT2 + oc];
#pragma unroll
        for (int si = 0; si < 4; si++) {
            int s = 4 * sq + si;
#pragma unroll
            for (int p = 0; p < 7; p++) {
                float v = acc2[si][p] * sc + sh;
                v = v > 0.f ? v : 0.f;
                unsigned short hi = f2bf_rn(v);
                unsigned short lo = f2bf_rn(v - bf2f(hi));
                size_t o = (size_t)(rbase + s) * 448 + p * 64 + oc;
                outH[o] = hi; outL[o] = lo;
            }
        }
    }
}

// ---------------- dual-problem hybrid MFMA GEMM (R6-proven body) ----------------
// per problem: out[m][n] = sum_k A(m,k)*Bt[n,k] + bias[n]; M=N=512; 16 blocks each
struct GArg {
    const unsigned short *A0h, *A0l;
    const _Float16* A1;
    const unsigned short *Bh, *Bl;
    const float* bias;
    float* outp;
    int lda0, K0, lda1, K;
};

__global__ __launch_bounds__(256, 2) void mgemm2(GArg A, GArg B, int nA)
{
    bool first = ((int)blockIdx.x < nA);
    GArg g = first ? A : B;
    int idx = first ? blockIdx.x : (blockIdx.x - nA);

    __shared__ __align__(16) unsigned short lAh[128 * 32];
    __shared__ __align__(16) unsigned short lAl[128 * 32];
    __shared__ __align__(16) unsigned short lBh[128 * 32];
    __shared__ __align__(16) unsigned short lBl[128 * 32];

    int tid = threadIdx.x;
    int m0 = (idx >> 2) * 128, n0 = (idx & 3) * 128;
    int l = tid & 63, w = tid >> 6;
    int wm = w >> 1, wn = w & 1;
    int lr = l & 15, lk = l >> 4;

    int srow = w * 16 + (l >> 2);
    int skoff = (l & 3) * 8;

    f32x4 acc[4][4];
#pragma unroll
    for (int i = 0; i < 4; i++)
#pragma unroll
        for (int j = 0; j < 4; j++) acc[i][j] = (f32x4){0.f, 0.f, 0.f, 0.f};

    for (int kt = 0; kt < g.K; kt += 32) {
        bool seg0 = (kt < g.K0);
        __syncthreads();
#pragma unroll
        for (int hh = 0; hh < 2; hh++) {
            size_t arow = (size_t)(m0 + hh * 64 + srow);
            size_t brow = (size_t)(n0 + hh * 64 + srow);
            char* dA  = (char*)lAh + hh * 4096 + w * 1024;
            char* dAl = (char*)lAl + hh * 4096 + w * 1024;
            char* dB  = (char*)lBh + hh * 4096 + w * 1024;
            char* dBl = (char*)lBl + hh * 4096 + w * 1024;
            if (seg0) {
                gload16(g.A0h + arow * g.lda0 + kt + skoff, dA);
                gload16(g.A0l + arow * g.lda0 + kt + skoff, dAl);
                gload16(g.Bl + brow * g.K + kt + skoff, dBl);
            } else {
                gload16(g.A1 + arow * g.lda1 + (kt - g.K0) + skoff, dA);
            }
            gload16(g.Bh + brow * g.K + kt + skoff, dB);
        }
        __syncthreads();

        if (seg0) {
            short8 fah[4], fal[4], fbh[4], fbl[4];
#pragma unroll
            for (int mf = 0; mf < 4; mf++) {
                int row = wm * 64 + mf * 16 + lr;
                fah[mf] = *(const short8*)&lAh[row * 32 + lk * 8];
                fal[mf] = *(const short8*)&lAl[row * 32 + lk * 8];
            }
#pragma unroll
            for (int nf = 0; nf < 4; nf++) {
                int row = wn * 64 + nf * 16 + lr;
                fbh[nf] = *(const short8*)&lBh[row * 32 + lk * 8];
                fbl[nf] = *(const short8*)&lBl[row * 32 + lk * 8];
            }
#pragma unroll
            for (int mf = 0; mf < 4; mf++)
#pragma unroll
                for (int nf = 0; nf < 4; nf++) {
                    acc[mf][nf] = __builtin_amdgcn_mfma_f32_16x16x32_bf16(
                        fah[mf], fbh[nf], acc[mf][nf], 0, 0, 0);
                    acc[mf][nf] = __builtin_amdgcn_mfma_f32_16x16x32_bf16(
                        fah[mf], fbl[nf], acc[mf][nf], 0, 0, 0);
                    acc[mf][nf] = __builtin_amdgcn_mfma_f32_16x16x32_bf16(
                        fal[mf], fbh[nf], acc[mf][nf], 0, 0, 0);
                }
        } else {
            half8 fah[4], fbh[4];
#pragma unroll
            for (int mf = 0; mf < 4; mf++) {
                int row = wm * 64 + mf * 16 + lr;
                fah[mf] = *(const half8*)&lAh[row * 32 + lk * 8];
            }
#pragma unroll
            for (int nf = 0; nf < 4; nf++) {
                int row = wn * 64 + nf * 16 + lr;
                fbh[nf] = *(const half8*)&lBh[row * 32 + lk * 8];
            }
#pragma unroll
            for (int mf = 0; mf < 4; mf++)
#pragma unroll
                for (int nf = 0; nf < 4; nf++)
                    acc[mf][nf] = __builtin_amdgcn_mfma_f32_16x16x32_f16(
                        fah[mf], fbh[nf], acc[mf][nf], 0, 0, 0);
        }
    }

#pragma unroll
    for (int nf = 0; nf < 4; nf++) {
        int gcol = n0 + wn * 64 + nf * 16 + lr;
        float bv = g.bias[gcol];
#pragma unroll
        for (int mf = 0; mf < 4; mf++) {
            int grow = m0 + wm * 64 + mf * 16 + lk * 4;
#pragma unroll
            for (int q = 0; q < 4; q++)
                g.outp[(size_t)(grow + q) * 512 + gcol] = acc[mf][nf][q] + bv;
        }
    }
}

// ---------------- dual-problem LSTM single step (R4/R6-proven body) ----------------
// mode 0: seqf bf16 H/L [b][128]; 1: seq1b f16 [t][b][128]; 2: H1F f32 if t==99
struct SArg {
    const float* Xpre; const float* whh;
    float *sh, *sc;
    unsigned short *oH, *oL;
    _Float16* o16;
    float* oF;
    int mode, t;
};

__global__ __launch_bounds__(512) void scan2(SArg A, SArg B, int nA)
{
    bool first = ((int)blockIdx.x < nA);
    SArg s = first ? A : B;
    int r0 = (first ? blockIdx.x : (blockIdx.x - nA)) * 2;
    int g = threadIdx.x;

    __shared__ __align__(16) float h_lds[2][128];
    __shared__ float c_lds[2][128];
    __shared__ float g_lds[2][512];

    float w[128];
#pragma unroll
    for (int k = 0; k < 128; k += 4) {
        float4 wv = *(const float4*)&s.whh[(size_t)g * 128 + k];
        w[k] = wv.x; w[k + 1] = wv.y; w[k + 2] = wv.z; w[k + 3] = wv.w;
    }
    if (g < 256) {
        int r = g >> 7, j = g & 127;
        h_lds[r][j] = s.sh[(size_t)(r0 + r) * 128 + j];
        c_lds[r][j] = s.sc[(size_t)(r0 + r) * 128 + j];
    }
    __syncthreads();

    float acc0 = s.Xpre[(size_t)(r0 + 0) * 512 + g];
    float acc1 = s.Xpre[(size_t)(r0 + 1) * 512 + g];
#pragma unroll
    for (int k = 0; k < 128; k += 4) {
        float4 h0 = *(const float4*)&h_lds[0][k];
        float4 h1 = *(const float4*)&h_lds[1][k];
        acc0 += w[k] * h0.x + w[k + 1] * h0.y + w[k + 2] * h0.z + w[k + 3] * h0.w;
        acc1 += w[k] * h1.x + w[k + 1] * h1.y + w[k + 2] * h1.z + w[k + 3] * h1.w;
    }
    g_lds[0][g] = acc0;
    g_lds[1][g] = acc1;
    __syncthreads();
    if (g < 256) {
        int r = g >> 7, j = g & 127;
        float gi = sigmoidf_(g_lds[r][j]);
        float gf = sigmoidf_(g_lds[r][128 + j]);
        float gg = tanhf_(g_lds[r][256 + j]);
        float go = sigmoidf_(g_lds[r][384 + j]);
        float c = gf * c_lds[r][j] + gi * gg;
        float h = go * tanhf_(c);
        s.sh[(size_t)(r0 + r) * 128 + j] = h;
        s.sc[(size_t)(r0 + r) * 128 + j] = c;
        if (s.mode == 0) {
            size_t o = (size_t)(r0 + r) * 128 + j;
            unsigned short hi = f2bf_rn(h);
            s.oH[o] = hi;
            s.oL[o] = f2bf_rn(h - bf2f(hi));
        } else if (s.mode == 1) {
            s.o16[((size_t)s.t * 512 + r0 + r) * 128 + j] = (_Float16)h;
        } else if (s.t == T_STEPS - 1) {
            s.oF[(size_t)(r0 + r) * 128 + j] = h;
        }
    }
}

// ---------------- final: FC head (layer1-bwd step folded into xp1b gates) ---------
__global__ __launch_bounds__(128) void final_kernel(
    const float* __restrict__ h1f, const float* __restrict__ xp1b,
    const float* __restrict__ fc1w, const float* __restrict__ fc1b,
    const float* __restrict__ fc2w, const float* __restrict__ fc2b,
    float* __restrict__ out)
{
    int b = blockIdx.x, tid = threadIdx.x;
    __shared__ float last[256];
    __shared__ float f1[64];
    {
        int j = tid;
        float gi = sigmoidf_(xp1b[(size_t)b * 512 + j]);
        float gg = tanhf_(xp1b[(size_t)b * 512 + 256 + j]);
        float go = sigmoidf_(xp1b[(size_t)b * 512 + 384 + j]);
        float c = gi * gg;                  // h0 = c0 = 0
        last[128 + j] = go * tanhf_(c);
        last[j] = h1f[(size_t)b * 128 + j];
    }
    __syncthreads();
    if (tid < 64) {
        float a = fc1b[tid];
        for (int k = 0; k < 256; k++) a += last[k] * fc1w[tid * 256 + k];
        f1[tid] = a > 0.f ? a : 0.f;
    }
    __syncthreads();
    if (tid < 2) {
        float a = fc2b[tid];
        for (int k = 0; k < 64; k++) a += f1[k] * fc2w[tid * 64 + k];
        out[b * 2 + tid] = a;
    }
}

extern "C" void kernel_launch(void* const* d_in, const int* in_sizes, int n_in,
                              void* d_out, int out_size, void* d_ws, size_t ws_size,
                              hipStream_t stream)
{
    const float* x     = (const float*)d_in[0];
    const float* c1w   = (const float*)d_in[1];
    const float* c1b   = (const float*)d_in[2];
    const float* g1    = (const float*)d_in[3];
    const float* b1    = (const float*)d_in[4];
    const float* m1    = (const float*)d_in[5];
    const float* v1    = (const float*)d_in[6];
    const float* c2w   = (const float*)d_in[7];
    const float* c2b   = (const float*)d_in[8];
    const float* g2    = (const float*)d_in[9];
    const float* b2    = (const float*)d_in[10];
    const float* m2    = (const float*)d_in[11];
    const float* v2    = (const float*)d_in[12];
    const float* wih0f = (const float*)d_in[13];
    const float* whh0f = (const float*)d_in[14];
    const float* bih0f = (const float*)d_in[15];
    const float* bhh0f = (const float*)d_in[16];
    const float* wih0b = (const float*)d_in[17];
    const float* whh0b = (const float*)d_in[18];
    const float* bih0b = (const float*)d_in[19];
    const float* bhh0b = (const float*)d_in[20];
    const float* wih1f = (const float*)d_in[21];
    const float* whh1f = (const float*)d_in[22];
    const float* bih1f = (const float*)d_in[23];
    const float* bhh1f = (const float*)d_in[24];
    const float* wih1b = (const float*)d_in[25];
    const float* bih1b = (const float*)d_in[27];
    const float* bhh1b = (const float*)d_in[28];
    const float* fc1w  = (const float*)d_in[29];
    const float* fc1b  = (const float*)d_in[30];
    const float* fc2w  = (const float*)d_in[31];
    const float* fc2b  = (const float*)d_in[32];

    float* ws  = (float*)d_ws;
    unsigned short* wsH = (unsigned short*)d_ws;
    float* out = (float*)d_out;

    unsigned short* cnnH = wsH + (size_t)OFF_CNNHL * 2;
    unsigned short* cnnL = cnnH + 229376;
    float* xpre0 = ws + OFF_XPRE0;
    float* xpre1 = ws + OFF_XPRE1;
    unsigned short* seqfH = wsH + (size_t)OFF_SEQF * 2;
    unsigned short* seqfL = seqfH + 65536;
    _Float16* seq1b = (_Float16*)(ws + OFF_SEQ1B);

    const unsigned short* W0FH = wsH + (size_t)OFF_W0FH * 2;
    const unsigned short* W0FL = wsH + (size_t)OFF_W0FL * 2;
    const unsigned short* W0BH = wsH + (size_t)OFF_W0BH * 2;
    const unsigned short* W0BL = wsH + (size_t)OFF_W0BL * 2;
    const unsigned short* W1FBH = wsH + (size_t)OFF_W1FBH * 2;
    const unsigned short* W1FBL = wsH + (size_t)OFF_W1FBL * 2;
    const unsigned short* W1BBH = wsH + (size_t)OFF_W1BBH * 2;
    const unsigned short* W1BBL = wsH + (size_t)OFF_W1BBL * 2;

    float* st = ws + OFF_STATE;   // h0b,c0b,h0f,c0f,h1f,c1f

    // 1. prep
    hipLaunchKernelGGL(prep_kernel, dim3(7241), dim3(256), 0, stream,
                       c1w, c1b, g1, b1, m1, v1, c2w, c2b, g2, b2, m2, v2,
                       wih0f, wih0b, wih1f, wih1b,
                       bih0f, bhh0f, bih0b, bhh0b, bih1f, bhh1f, bih1b, bhh1b, ws);

    // 2. phase 1: layer-0 backward, t = 99..0 (3 dispatches/step)
    for (int i = 0; i < T_STEPS; i++) {
        int t = T_STEPS - 1 - i;
        hipLaunchKernelGGL(cnn_kernel, dim3(32), dim3(256), 0, stream,
                           x, ws, cnnH, cnnL, t);
        GArg gB = { cnnH, cnnL, (const _Float16*)nullptr, W0BH, W0BL,
                    ws + OFF_BIASL0 + 512, xpre0, 448, 448, 0, 448 };
        hipLaunchKernelGGL(mgemm2, dim3(16), dim3(256), 0, stream, gB, gB, 16);
        SArg sB = { xpre0, whh0b, st, st + 65536,
                    nullptr, nullptr, seq1b, nullptr, 1, t };
        hipLaunchKernelGGL(scan2, dim3(256), dim3(512), 0, stream, sB, sB, 256);
    }

    // 3. phase 2: layer-0 fwd (step i) + layer-1 fwd (step i-1), merged pairs
    for (int i = 0; i < T_STEPS; i++) {
        hipLaunchKernelGGL(cnn_kernel, dim3(32), dim3(256), 0, stream,
                           x, ws, cnnH, cnnL, i);
        GArg gF = { cnnH, cnnL, (const _Float16*)nullptr, W0FH, W0FL,
                    ws + OFF_BIASL0, xpre0, 448, 448, 0, 448 };
        SArg sF = { xpre0, whh0f, st + 131072, st + 196608,
                    seqfH, seqfL, nullptr, nullptr, 0, i };
        if (i == 0) {
            hipLaunchKernelGGL(mgemm2, dim3(16), dim3(256), 0, stream, gF, gF, 16);
            hipLaunchKernelGGL(scan2, dim3(256), dim3(512), 0, stream, sF, sF, 256);
        } else {
            GArg g1a = { seqfH, seqfL, seq1b + (size_t)(i - 1) * 65536,
                         W1FBH, W1FBL, ws + OFF_BIAS1F, xpre1, 128, 128, 128, 256 };
            SArg s1 = { xpre1, whh1f, st + 262144, st + 327680,
                        nullptr, nullptr, nullptr, ws + OFF_H1F, 2, i - 1 };
            hipLaunchKernelGGL(mgemm2, dim3(32), dim3(256), 0, stream, gF, g1a, 16);
            hipLaunchKernelGGL(scan2, dim3(512), dim3(512), 0, stream, sF, s1, 256);
        }
    }

    // 4. tail: {gemm1(99) || gemmXP}, scan1(99), final
    {
        GArg g1t = { seqfH, seqfL, seq1b + (size_t)99 * 65536,
                     W1FBH, W1FBL, ws + OFF_BIAS1F, xpre1, 128, 128, 128, 256 };
        GArg gXP = { seqfH, seqfL, seq1b + (size_t)99 * 65536,
                     W1BBH, W1BBL, ws + OFF_BIAS1B, ws + OFF_XP1B, 128, 128, 128, 256 };
        hipLaunchKernelGGL(mgemm2, dim3(32), dim3(256), 0, stream, g1t, gXP, 16);
        SArg s1t = { xpre1, whh1f, st + 262144, st + 327680,
                     nullptr, nullptr, nullptr, ws + OFF_H1F, 2, 99 };
        hipLaunchKernelGGL(scan2, dim3(256), dim3(512), 0, stream, s1t, s1t, 256);
    }

    hipLaunchKernelGGL(final_kernel, dim3(512), dim3(128), 0, stream,
                       ws + OFF_H1F, ws + OFF_XP1B, fc1w, fc1b, fc2w, fc2b, out);

    (void)in_sizes; (void)n_in; (void)out_size; (void)ws_size;
}